// Round 5
// baseline (368.790 us; speedup 1.0000x reference)
//
#include <hip/hip_runtime.h>
#include <type_traits>

typedef float v2f __attribute__((ext_vector_type(2)));

namespace {
constexpr int HH = 512, WW = 512;
constexpr int KS = 11, PADR = 5;
constexpr int BH = 32;            // output rows per block (band)
constexpr int SR = 4;             // rows per slab
constexpr int NSLAB = BH / SR;    // 8
constexpr int WIN = SR + 2*PADR;  // 14-row sliding window
constexpr int PITCH = 528;        // 8 pad | 512 cols | 8 pad  (16B-aligned rows)
constexpr int NT = 256;
constexpr float SSIM_C1 = 1.0e-4f;
constexpr float SSIM_C2 = 9.0e-4f;
}

// Block = full-width 512x32 band (768 blocks = exactly 3/CU, zero tail).
// Phase 1 (vertical): thread owns col-pair (2t,2t+1) as v2f; 14-deep x/y
//   register windows slide down the band, so each input pixel is loaded ONCE
//   (vs 11-22x in R4) and squared once per slab; vertical 11-tap sums are
//   packed v_pk_fma_f32. Full width => no horizontal halo recompute.
// Phase 2 (horizontal, R4-proven scalar logic): thread = 4-col quad x 2 rows;
//   window read as 5 aligned ds_read_b128 at canonical 16B/lane stride
//   (conflict-free); SSIM formula; float4 store.
// LDS 42.2 KB => 3 blocks/CU; launch_bounds(256,3) keeps VGPR budget ~170
// (R2 lesson: tighter caps spill to scratch).
__global__ __launch_bounds__(NT, 3) void ssim_fused(
    const float* __restrict__ x, const float* __restrict__ y,
    const float* __restrict__ kern, float* __restrict__ out)
{
    __shared__ __align__(16) float vb[5][SR][PITCH];   // 42240 B

    const int bid = blockIdx.x;
    const int plane = bid >> 4;          // 48 planes
    const int band = bid & 15;           // 16 bands
    const int R0 = band << 5;

    const float* __restrict__ xp = x + (size_t)plane * (HH * WW);
    const float* __restrict__ yp = y + (size_t)plane * (HH * WW);
    float* __restrict__ op = out + (size_t)plane * (HH * WW);

    // 1D gaussian from 2D kernel (exact for outer products)
    float wt[KS];
    {
        const float inv = rsqrtf(kern[5 * KS + 5]);
#pragma unroll
        for (int i = 0; i < KS; ++i) wt[i] = kern[5 * KS + i] * inv;
    }

    const int t = threadIdx.x;
    const int c2 = 2 * t;                // owned column pair
    const int q  = t & 127;              // phase-2 col quad (cols 4q..4q+3)
    const int rb = (t >> 7) * 2;         // phase-2 first slab-row (0 or 2)

    // zero the horizontal pad columns (idx 0..7 = cols -8..-1, 520..527 =
    // cols 512..519) once; visible to phase 2 after the first barrier.
    for (int i = t; i < 5 * SR * 16; i += NT) {
        const int st = i >> 6;
        const int rem = i & 63;
        const int r = rem >> 4;
        const int j = rem & 15;
        vb[st][r][(j < 8) ? j : (512 + j)] = 0.f;
    }

    auto body = [&](auto edge_tag) {
        constexpr bool EDGE = decltype(edge_tag)::value;
        const v2f zz = {0.f, 0.f};

        auto ldrow = [&](int row, v2f& vx, v2f& vy) {
            if (!EDGE || ((unsigned)row < (unsigned)HH)) {   // uniform branch
                vx = *(const v2f*)(xp + row * WW + c2);
                vy = *(const v2f*)(yp + row * WW + c2);
            } else { vx = zz; vy = zz; }
        };

        // prime the sliding windows with input rows R0-5 .. R0+8
        v2f xw[WIN], yw[WIN];
#pragma unroll
        for (int i = 0; i < WIN; ++i) ldrow(R0 - PADR + i, xw[i], yw[i]);

        for (int s = 0; s < NSLAB; ++s) {
            // ---- phase 1: vertical 11-tap blur of 5 stats for SR rows ----
            // ux, uy straight from the windows
#pragma unroll
            for (int j = 0; j < SR; ++j) {
                v2f a = wt[0] * xw[j];
#pragma unroll
                for (int k = 1; k < KS; ++k) a += wt[k] * xw[j + k];
                *(v2f*)&vb[0][j][8 + c2] = a;
            }
#pragma unroll
            for (int j = 0; j < SR; ++j) {
                v2f a = wt[0] * yw[j];
#pragma unroll
                for (int k = 1; k < KS; ++k) a += wt[k] * yw[j + k];
                *(v2f*)&vb[1][j][8 + c2] = a;
            }
            // uxx / uyy / uxy via per-stat product temps (squares computed
            // once per slab, not once per tap)
            {
                v2f tmp[WIN];
#pragma unroll
                for (int i = 0; i < WIN; ++i) tmp[i] = xw[i] * xw[i];
#pragma unroll
                for (int j = 0; j < SR; ++j) {
                    v2f a = wt[0] * tmp[j];
#pragma unroll
                    for (int k = 1; k < KS; ++k) a += wt[k] * tmp[j + k];
                    *(v2f*)&vb[2][j][8 + c2] = a;
                }
            }
            {
                v2f tmp[WIN];
#pragma unroll
                for (int i = 0; i < WIN; ++i) tmp[i] = yw[i] * yw[i];
#pragma unroll
                for (int j = 0; j < SR; ++j) {
                    v2f a = wt[0] * tmp[j];
#pragma unroll
                    for (int k = 1; k < KS; ++k) a += wt[k] * tmp[j + k];
                    *(v2f*)&vb[3][j][8 + c2] = a;
                }
            }
            {
                v2f tmp[WIN];
#pragma unroll
                for (int i = 0; i < WIN; ++i) tmp[i] = xw[i] * yw[i];
#pragma unroll
                for (int j = 0; j < SR; ++j) {
                    v2f a = wt[0] * tmp[j];
#pragma unroll
                    for (int k = 1; k < KS; ++k) a += wt[k] * tmp[j + k];
                    *(v2f*)&vb[4][j][8 + c2] = a;
                }
            }
            __syncthreads();

            // prefetch next slab's 4 input rows (issued before phase-2
            // compute so L2/HBM latency hides under ~500 cycles of math)
            v2f nx[SR], ny[SR];
            if (s + 1 < NSLAB) {
#pragma unroll
                for (int j = 0; j < SR; ++j)
                    ldrow(R0 - PADR + WIN + s * SR + j, nx[j], ny[j]);
            }

            // ---- phase 2: horizontal 11-tap blur + SSIM, 2 rows x 4 cols --
#pragma unroll
            for (int rr = 0; rr < 2; ++rr) {
                const int r = rb + rr;
                float u[5][4];
#pragma unroll
                for (int st = 0; st < 5; ++st) {
                    float wnd[20];
#pragma unroll
                    for (int ch = 0; ch < 5; ++ch) {
                        const float4 v = *(const float4*)&vb[st][r][4 * q + 4 * ch];
                        wnd[4 * ch + 0] = v.x;
                        wnd[4 * ch + 1] = v.y;
                        wnd[4 * ch + 2] = v.z;
                        wnd[4 * ch + 3] = v.w;
                    }
                    // output col 4q+d, tap k -> storage idx 4q + d+3+k
#pragma unroll
                    for (int d = 0; d < 4; ++d) {
                        float a = wt[0] * wnd[d + 3];
#pragma unroll
                        for (int k = 1; k < KS; ++k) a += wt[k] * wnd[d + 3 + k];
                        u[st][d] = a;
                    }
                }
                float4 o;
#pragma unroll
                for (int d = 0; d < 4; ++d) {
                    const float ux = u[0][d], uy = u[1][d];
                    const float uxx = u[2][d], uyy = u[3][d], uxy = u[4][d];
                    const float vx  = uxx - ux * ux;
                    const float vy  = uyy - uy * uy;
                    const float vxy = uxy - ux * uy;
                    const float a1 = 2.f * ux * uy + SSIM_C1;
                    const float a2 = 2.f * vxy + SSIM_C2;
                    const float b1 = ux * ux + uy * uy + SSIM_C1;
                    const float b2 = vx + vy + SSIM_C2;
                    (&o.x)[d] = (a1 * a2) * __builtin_amdgcn_rcpf(b1 * b2);
                }
                *(float4*)&op[(size_t)(R0 + s * SR + r) * WW + 4 * q] = o;
            }
            __syncthreads();   // vb reused by next slab

            // slide the windows down by SR rows
            if (s + 1 < NSLAB) {
#pragma unroll
                for (int i = 0; i < WIN - SR; ++i) {
                    xw[i] = xw[i + SR];
                    yw[i] = yw[i + SR];
                }
#pragma unroll
                for (int j = 0; j < SR; ++j) {
                    xw[WIN - SR + j] = nx[j];
                    yw[WIN - SR + j] = ny[j];
                }
            }
        }
    };

    // bands 1..14 never touch rows <0 or >=512 -> unguarded loads
    if (band >= 1 && band <= 14) body(std::false_type{});
    else                         body(std::true_type{});
}

extern "C" void kernel_launch(void* const* d_in, const int* in_sizes, int n_in,
                              void* d_out, int out_size, void* d_ws, size_t ws_size,
                              hipStream_t stream) {
    const float* x    = (const float*)d_in[0];
    const float* y    = (const float*)d_in[1];
    const float* kern = (const float*)d_in[2];
    float* out = (float*)d_out;

    const int nplanes = in_sizes[0] / (HH * WW);      // 48
    const int nblocks = nplanes * (HH / BH);          // 768

    ssim_fused<<<dim3(nblocks), dim3(NT), 0, stream>>>(x, y, kern, out);
}